// Round 16
// baseline (185.461 us; speedup 1.0000x reference)
//
#include <hip/hip_runtime.h>

#define KDIM   32768
#define NCHUNK 4                    // split-K factor
#define CHUNK  (KDIM / NCHUNK)      // 8192 floats per chunk
#define TPB    256                  // threads per block (4 waves)

// Zero the 200 output floats (d_out is re-poisoned to 0xAA before every launch).
__global__ void zero_out(float* __restrict__ out, int n) {
    int i = blockIdx.x * blockDim.x + threadIdx.x;
    if (i < n) out[i] = 0.f;
}

// 800 blocks: block b handles output (b>>2), K-chunk (b&3).
// out_idx < 100 -> dgm1[i] = dot(I1[row(inds1,i)], p0)
// out_idx >=100 -> dgm2[i] = dot(I2[row(inds2,i)], p1)
__global__ __launch_bounds__(TPB) void cubical_gather_matvec_splitk(
    const float* __restrict__ p0, const float* __restrict__ p1,
    const float* __restrict__ I1, const float* __restrict__ I2,
    const int* __restrict__ inds1, const int* __restrict__ inds2,
    float* __restrict__ out)
{
    const int b       = blockIdx.x;
    const int out_idx = b >> 2;          // 0..199
    const int chunk   = b & (NCHUNK - 1);

    const float* p;
    const float* I;
    const int* inds;
    int i;
    if (out_idx < 100) { p = p0; I = I1; inds = inds1; i = out_idx; }
    else               { p = p1; I = I2; inds = inds2; i = out_idx - 100; }

    const int r = inds[2 * i];
    const int c = inds[2 * i + 1];
    const float* row = I + (size_t)(r * 28 + c) * KDIM + (size_t)chunk * CHUNK;
    const float* pc  = p + (size_t)chunk * CHUNK;

    const int tid = threadIdx.x;
    const float4* row4 = (const float4*)row;
    const float4* p4   = (const float4*)pc;

    // CHUNK/4 = 2048 float4; 256 threads -> 8 iterations, fully unrolled
    // (16 outstanding 16B loads per thread for latency hiding).
    float acc = 0.f;
    #pragma unroll 8
    for (int j = tid; j < CHUNK / 4; j += TPB) {
        float4 a = row4[j];
        float4 v = p4[j];
        acc += a.x * v.x + a.y * v.y + a.z * v.z + a.w * v.w;
    }

    // wave-64 shuffle reduce
    #pragma unroll
    for (int off = 32; off > 0; off >>= 1)
        acc += __shfl_down(acc, off, 64);

    __shared__ float s[4];
    const int lane = tid & 63;
    const int wid  = tid >> 6;
    if (lane == 0) s[wid] = acc;
    __syncthreads();
    if (tid == 0) {
        float t = s[0] + s[1] + s[2] + s[3];
        atomicAdd(&out[out_idx], t);   // device-scope, safe across XCDs
    }
}

extern "C" void kernel_launch(void* const* d_in, const int* in_sizes, int n_in,
                              void* d_out, int out_size, void* d_ws, size_t ws_size,
                              hipStream_t stream) {
    const float* p0    = (const float*)d_in[0];
    const float* p1    = (const float*)d_in[1];
    const float* I1    = (const float*)d_in[2];
    const float* I2    = (const float*)d_in[3];
    const int*   inds1 = (const int*)d_in[4];
    const int*   inds2 = (const int*)d_in[5];
    float* out = (float*)d_out;

    zero_out<<<1, 256, 0, stream>>>(out, out_size);
    cubical_gather_matvec_splitk<<<200 * NCHUNK, TPB, 0, stream>>>(
        p0, p1, I1, I2, inds1, inds2, out);
}